// Round 11
// baseline (257.615 us; speedup 1.0000x reference)
//
#include <hip/hip_runtime.h>
#include <hip/hip_bf16.h>
#include <math.h>

// DecoderSphere B=16,T=65536,D=32. Round 11 = round 10 resubmitted (GPU
// acquisition timed out; kernel never ran). PHASE SPLIT (ablation + win).
// R8/R9 proved duration (~130us) is invariant to occupancy (20% vs 40%) and
// to VALU count (-22%) -> the floor is stall time whose owner (interp gather
// latency vs resnet MFMA chain) counters can't separate in a fused kernel.
// Split: kernel A (interp -> cf bf16[32]/pt in workspace, 64MB, L3-resident)
// runs at high occupancy with nothing but gathers; kernel B (resnet) reads
// cf with ONE coalesced 1KB load per tile, no scatter, no cf-LDS.
// rocprof now times each phase separately = direct ablation.
// Falls back to the fused R8 kernel if ws_size is too small.

typedef __attribute__((ext_vector_type(8))) short short8;
typedef __attribute__((ext_vector_type(4))) float f32x4;

#define CFW 36   // fused-path cf row stride in dwords

static __device__ __forceinline__ unsigned short f2bf(float x) {
    __hip_bfloat16 b = __float2bfloat16(x);
    unsigned short u;
    __builtin_memcpy(&u, &b, 2);
    return u;
}

// relu + pack two f32x4 accumulators into one bf16 x8 B-fragment (k=8q+j)
// via v_cvt_pk_bf16_f32 (lo = src0, hi = src1; HW RNE).
static __device__ __forceinline__ short8 pack2(f32x4 a, f32x4 b) {
    const float a0 = fmaxf(a[0], 0.f), a1 = fmaxf(a[1], 0.f);
    const float a2 = fmaxf(a[2], 0.f), a3 = fmaxf(a[3], 0.f);
    const float b0 = fmaxf(b[0], 0.f), b1 = fmaxf(b[1], 0.f);
    const float b2 = fmaxf(b[2], 0.f), b3 = fmaxf(b[3], 0.f);
    unsigned u0, u1, u2, u3;
    asm("v_cvt_pk_bf16_f32 %0, %1, %2" : "=v"(u0) : "v"(a0), "v"(a1));
    asm("v_cvt_pk_bf16_f32 %0, %1, %2" : "=v"(u1) : "v"(a2), "v"(a3));
    asm("v_cvt_pk_bf16_f32 %0, %1, %2" : "=v"(u2) : "v"(b0), "v"(b1));
    asm("v_cvt_pk_bf16_f32 %0, %1, %2" : "=v"(u3) : "v"(b2), "v"(b3));
    union { unsigned u[4]; short8 s; } cv;
    cv.u[0] = u0; cv.u[1] = u1; cv.u[2] = u2; cv.u[3] = u3;
    return cv.s;
}

static __device__ __forceinline__ f32x4 bf4_to_f32(short8 cu, int base) {
    f32x4 r;
#pragma unroll
    for (int e = 0; e < 4; ++e) {
        unsigned u = ((unsigned)(unsigned short)cu[base + e]) << 16;  // exact
        float f; __builtin_memcpy(&f, &u, 4);
        r[e] = f;
    }
    return r;
}

// ---- prep: w0/w1 -> bf16 A-fragments in fragment order (as R4-R9).
__global__ __launch_bounds__(256) void prep_weights(
    const float* __restrict__ w0g,
    const float* __restrict__ w1g,
    unsigned short* __restrict__ wsf)
{
    const int o = blockIdx.x * 256 + threadIdx.x;
    if (o >= 1280) return;
    const int lane = o & 63;
    const int h    = (o >> 6) & 1;
    const int mat  = (o >> 7) & 1;
    const int i    = o >> 8;
    const int q = lane >> 4, m15 = lane & 15;
    const int g0 = 8 * (m15 >> 2) + 4 * h + (m15 & 3);
    const float* src = (mat ? w1g : w0g) + i * 1024 + g0;
    union { unsigned short s[8]; short8 v; } r;
#pragma unroll
    for (int j = 0; j < 8; ++j)
        r.s[j] = f2bf(src[(8 * q + j) * 32]);
    *(short8*)(wsf + (size_t)o * 8) = r.v;
}

// ================= kernel A: interpolation -> cf bf16[32] per point ==========
__global__ __launch_bounds__(256) void interp_cf(
    const float* __restrict__ p,
    const float* __restrict__ c,
    unsigned short* __restrict__ cfw)
{
    const float PI_F = 3.1415927410125732f;
    const int g = blockIdx.x * 256 + threadIdx.x;
    const int b = g >> 16;                      // T = 65536

    const float px = p[3 * g + 0];
    const float py = p[3 * g + 1];
    const float pz = p[3 * g + 2];

    const float lat = 90.0f - (atan2f(pz, sqrtf(px * px + py * py)) * 180.0f) / PI_F;
    const float mer = fmodf(360.0f + (atan2f(py, px) * 180.0f) / PI_F, 360.0f);

    const int xg = (int)floorf(mer / 5.625f);
    const int yg = (int)floorf(lat / 2.8125f);

    const int xl = (xg + 63) & 63;
    const int xr = (xg + 1) & 63;
    const int ylo = yg - 1 - ((yg - 1) >> 6);
    const int yhi = yg + 1 - ((yg + 1) >> 6);

    const float dx = (float)(xr - xg);
    const float dy = (float)(yhi - yg);

    const int yloi = ylo < 63 ? ylo : 63;
    const int yhii = yhi < 63 ? yhi : 63;

    const float w11 = dx * dy;
    const float w12 = (1.0f - dx) * dy;
    const float w21 = dx * (1.0f - dy);
    const float w22 = (1.0f - dx) * (1.0f - dy);

    const float* gb  = c + (size_t)b * (64 * 64 * 32);
    const float* r11 = gb + (xl * 64 + yloi) * 32;
    const float* r12 = gb + (xr * 64 + yloi) * 32;
    const float* r21 = gb + (xl * 64 + yhii) * 32;
    const float* r22 = gb + (xr * 64 + yhii) * 32;

    union { unsigned u[16]; } ud;
#pragma unroll
    for (int d = 0; d < 32; d += 4) {
        const f32x4 a  = *(const f32x4*)(r11 + d);
        const f32x4 e  = *(const f32x4*)(r12 + d);
        const f32x4 f  = *(const f32x4*)(r21 + d);
        const f32x4 h4 = *(const f32x4*)(r22 + d);
        f32x4 v = w11 * a + w12 * e + w21 * f + w22 * h4;
        unsigned lo, hi;
        asm("v_cvt_pk_bf16_f32 %0, %1, %2" : "=v"(lo) : "v"(v[0]), "v"(v[1]));
        asm("v_cvt_pk_bf16_f32 %0, %1, %2" : "=v"(hi) : "v"(v[2]), "v"(v[3]));
        ud.u[d / 2]     = lo;
        ud.u[d / 2 + 1] = hi;
    }
    unsigned* dst = (unsigned*)(cfw + (size_t)g * 32);
#pragma unroll
    for (int k = 0; k < 16; k += 4)
        *(f32x4*)(dst + k) = *(f32x4*)(ud.u + k);   // 4x dwordx4 stores
}

// ================= kernel B: pure resnet (coalesced cf, no gathers) ==========
__global__ __launch_bounds__(256, 2) void decoder_split(
    const float* __restrict__ p,
    const float* __restrict__ fc_p_w,
    const float* __restrict__ fc_p_b,
    const float* __restrict__ b0g,
    const float* __restrict__ b1g,
    const float* __restrict__ fc_out_w,
    const float* __restrict__ fc_out_b,
    const unsigned short* __restrict__ wsf,
    const unsigned short* __restrict__ cfw,
    float* __restrict__ out)
{
    __shared__ float cb[512];
    const int tid  = threadIdx.x;
    const int wave = tid >> 6;
    const int lane = tid & 63;
    const int m15  = lane & 15;
    const int q    = lane >> 4;

    for (int t = tid; t < 481; t += 256) {
        float v;
        if      (t < 96)  v = fc_p_w[t];
        else if (t < 128) v = fc_p_b[t - 96];
        else if (t < 288) v = b0g[t - 128];
        else if (t < 448) v = b1g[t - 288];
        else if (t < 480) v = fc_out_w[t - 448];
        else              v = fc_out_b[0];
        cb[t] = v;
    }
    __syncthreads();

    const int gbase = blockIdx.x * 256 + wave * 64;

    // cf: one coalesced 16B/lane load per tile (lane's 8 feats of its point)
    f32x4 cf[4][2];
#pragma unroll
    for (int t = 0; t < 4; ++t) {
        const short8 cu = *(const short8*)(cfw + (size_t)(gbase + t * 16 + m15) * 32 + q * 8);
        cf[t][0] = bf4_to_f32(cu, 0);
        cf[t][1] = bf4_to_f32(cu, 4);
    }

    // net init from p (16 distinct points/tile, L1-broadcast)
    f32x4 net[4][2];
#pragma unroll
    for (int h = 0; h < 2; ++h) {
        const int fo = 8 * q + 4 * h;
        const f32x4 wx = *(const f32x4*)(cb + fo);
        const f32x4 wy = *(const f32x4*)(cb + 32 + fo);
        const f32x4 wz = *(const f32x4*)(cb + 64 + fo);
        const f32x4 bb = *(const f32x4*)(cb + 96 + fo);
#pragma unroll
        for (int t = 0; t < 4; ++t) {
            const int pt = gbase + t * 16 + m15;
            net[t][h] = p[3 * pt] * wx + p[3 * pt + 1] * wy + p[3 * pt + 2] * wz + bb;
        }
    }

    const short8* wsf8 = (const short8*)wsf;
    short8 cw00 = wsf8[lane];
    short8 cw01 = wsf8[64 + lane];
    short8 cw10 = wsf8[128 + lane];
    short8 cw11 = wsf8[192 + lane];

#pragma unroll 1
    for (int i = 0; i < 5; ++i) {
        const int ip = (i == 4) ? 0 : (i + 1);
        const short8 nw00 = wsf8[ip * 256 + lane];
        const short8 nw01 = wsf8[ip * 256 + 64 + lane];
        const short8 nw10 = wsf8[ip * 256 + 128 + lane];
        const short8 nw11 = wsf8[ip * 256 + 192 + lane];

        const int b0o = 128 + i * 32 + 8 * q;
        const int b1o = 288 + i * 32 + 8 * q;
        const f32x4 bias00 = *(const f32x4*)(cb + b0o);
        const f32x4 bias01 = *(const f32x4*)(cb + b0o + 4);
        const f32x4 bias10 = *(const f32x4*)(cb + b1o);
        const f32x4 bias11 = *(const f32x4*)(cb + b1o + 4);

        short8 xf[4];
#pragma unroll
        for (int t = 0; t < 4; ++t) {
            net[t][0] += cf[t][0];
            net[t][1] += cf[t][1];
            xf[t] = pack2(net[t][0], net[t][1]);
        }

        f32x4 hh[4][2];
#pragma unroll
        for (int t = 0; t < 4; ++t) {
            hh[t][0] = __builtin_amdgcn_mfma_f32_16x16x32_bf16(cw00, xf[t], bias00, 0, 0, 0);
            hh[t][1] = __builtin_amdgcn_mfma_f32_16x16x32_bf16(cw01, xf[t], bias01, 0, 0, 0);
        }
#pragma unroll
        for (int t = 0; t < 4; ++t) {
            const short8 hf = pack2(hh[t][0], hh[t][1]);
            net[t][0] = __builtin_amdgcn_mfma_f32_16x16x32_bf16(cw10, hf, net[t][0], 0, 0, 0);
            net[t][1] = __builtin_amdgcn_mfma_f32_16x16x32_bf16(cw11, hf, net[t][1], 0, 0, 0);
        }
#pragma unroll
        for (int t = 0; t < 4; ++t) {
            net[t][0] += bias10;
            net[t][1] += bias11;
        }
        cw00 = nw00; cw01 = nw01; cw10 = nw10; cw11 = nw11;
    }

    const f32x4 ow0 = *(const f32x4*)(cb + 448 + 8 * q);
    const f32x4 ow1 = *(const f32x4*)(cb + 448 + 8 * q + 4);
#pragma unroll
    for (int t = 0; t < 4; ++t) {
        float s = 0.f;
#pragma unroll
        for (int r = 0; r < 4; ++r)
            s += fmaxf(net[t][0][r], 0.f) * ow0[r] + fmaxf(net[t][1][r], 0.f) * ow1[r];
        s += __shfl_xor(s, 16, 64);
        s += __shfl_xor(s, 32, 64);
        if (q == 0)
            out[gbase + t * 16 + m15] = s + cb[480];
    }
}

// ================= fused fallback (exact R8 kernel) ==========================
__global__ __launch_bounds__(256, 2) void decoder_mfma(
    const float* __restrict__ p,
    const float* __restrict__ c,
    const float* __restrict__ fc_p_w,
    const float* __restrict__ fc_p_b,
    const float* __restrict__ b0g,
    const float* __restrict__ b1g,
    const float* __restrict__ fc_out_w,
    const float* __restrict__ fc_out_b,
    const unsigned short* __restrict__ wsf,
    float* __restrict__ out)
{
    __shared__ float lds[9728];
    const int tid  = threadIdx.x;
    const int wave = tid >> 6;
    const int lane = tid & 63;
    const int m15  = lane & 15;
    const int q    = lane >> 4;

    float* cfb = lds + wave * 2304;
    float* cb  = lds + 9216;

    for (int t = tid; t < 481; t += 256) {
        float v;
        if      (t < 96)  v = fc_p_w[t];
        else if (t < 128) v = fc_p_b[t - 96];
        else if (t < 288) v = b0g[t - 128];
        else if (t < 448) v = b1g[t - 288];
        else if (t < 480) v = fc_out_w[t - 448];
        else              v = fc_out_b[0];
        cb[t] = v;
    }
    __syncthreads();

    const float PI_F = 3.1415927410125732f;
    const int g = blockIdx.x * 256 + tid;
    const int b = g >> 16;

    const float px = p[3 * g + 0];
    const float py = p[3 * g + 1];
    const float pz = p[3 * g + 2];

    const float lat = 90.0f - (atan2f(pz, sqrtf(px * px + py * py)) * 180.0f) / PI_F;
    const float mer = fmodf(360.0f + (atan2f(py, px) * 180.0f) / PI_F, 360.0f);

    const int xg = (int)floorf(mer / 5.625f);
    const int yg = (int)floorf(lat / 2.8125f);

    const int xl = (xg + 63) & 63;
    const int xr = (xg + 1) & 63;
    const int ylo = yg - 1 - ((yg - 1) >> 6);
    const int yhi = yg + 1 - ((yg + 1) >> 6);

    const float dx = (float)(xr - xg);
    const float dy = (float)(yhi - yg);

    const int yloi = ylo < 63 ? ylo : 63;
    const int yhii = yhi < 63 ? yhi : 63;

    const float w11 = dx * dy;
    const float w12 = (1.0f - dx) * dy;
    const float w21 = dx * (1.0f - dy);
    const float w22 = (1.0f - dx) * (1.0f - dy);

    const float* gb  = c + (size_t)b * (64 * 64 * 32);
    const float* r11 = gb + (xl * 64 + yloi) * 32;
    const float* r12 = gb + (xr * 64 + yloi) * 32;
    const float* r21 = gb + (xl * 64 + yhii) * 32;
    const float* r22 = gb + (xr * 64 + yhii) * 32;

    float* cfr = cfb + lane * CFW;
#pragma unroll
    for (int d = 0; d < 32; d += 4) {
        const f32x4 a  = *(const f32x4*)(r11 + d);
        const f32x4 e  = *(const f32x4*)(r12 + d);
        const f32x4 f  = *(const f32x4*)(r21 + d);
        const f32x4 h4 = *(const f32x4*)(r22 + d);
        f32x4 v = w11 * a + w12 * e + w21 * f + w22 * h4;
        *(f32x4*)(cfr + d) = v;
    }
    {
        f32x4 pp = { px, py, pz, 0.f };
        *(f32x4*)(cfr + 32) = pp;
    }

    __builtin_amdgcn_wave_barrier();

    const short8* wsf8 = (const short8*)wsf;
    f32x4 net[4][2];
#pragma unroll
    for (int h = 0; h < 2; ++h) {
        const int fo = 8 * q + 4 * h;
        const f32x4 wx = *(const f32x4*)(cb + fo);
        const f32x4 wy = *(const f32x4*)(cb + 32 + fo);
        const f32x4 wz = *(const f32x4*)(cb + 64 + fo);
        const f32x4 bb = *(const f32x4*)(cb + 96 + fo);
#pragma unroll
        for (int t = 0; t < 4; ++t) {
            const f32x4 pp = *(const f32x4*)(cfb + (t * 16 + m15) * CFW + 32);
            net[t][h] = pp[0] * wx + pp[1] * wy + pp[2] * wz + bb;
        }
    }

    short8 cw00 = wsf8[lane];
    short8 cw01 = wsf8[64 + lane];
    short8 cw10 = wsf8[128 + lane];
    short8 cw11 = wsf8[192 + lane];

#pragma unroll 1
    for (int i = 0; i < 5; ++i) {
        const int ip = (i == 4) ? 0 : (i + 1);
        const short8 nw00 = wsf8[ip * 256 + lane];
        const short8 nw01 = wsf8[ip * 256 + 64 + lane];
        const short8 nw10 = wsf8[ip * 256 + 128 + lane];
        const short8 nw11 = wsf8[ip * 256 + 192 + lane];

        const int b0o = 128 + i * 32 + 8 * q;
        const int b1o = 288 + i * 32 + 8 * q;
        const f32x4 bias00 = *(const f32x4*)(cb + b0o);
        const f32x4 bias01 = *(const f32x4*)(cb + b0o + 4);
        const f32x4 bias10 = *(const f32x4*)(cb + b1o);
        const f32x4 bias11 = *(const f32x4*)(cb + b1o + 4);

        short8 xf[4];
#pragma unroll
        for (int t = 0; t < 4; ++t) {
            const int co = (t * 16 + m15) * CFW + 8 * q;
            net[t][0] += *(const f32x4*)(cfb + co);
            net[t][1] += *(const f32x4*)(cfb + co + 4);
            xf[t] = pack2(net[t][0], net[t][1]);
        }

        f32x4 hh[4][2];
#pragma unroll
        for (int t = 0; t < 4; ++t) {
            hh[t][0] = __builtin_amdgcn_mfma_f32_16x16x32_bf16(cw00, xf[t], bias00, 0, 0, 0);
            hh[t][1] = __builtin_amdgcn_mfma_f32_16x16x32_bf16(cw01, xf[t], bias01, 0, 0, 0);
        }
#pragma unroll
        for (int t = 0; t < 4; ++t) {
            const short8 hf = pack2(hh[t][0], hh[t][1]);
            net[t][0] = __builtin_amdgcn_mfma_f32_16x16x32_bf16(cw10, hf, net[t][0], 0, 0, 0);
            net[t][1] = __builtin_amdgcn_mfma_f32_16x16x32_bf16(cw11, hf, net[t][1], 0, 0, 0);
        }
#pragma unroll
        for (int t = 0; t < 4; ++t) {
            net[t][0] += bias10;
            net[t][1] += bias11;
        }
        cw00 = nw00; cw01 = nw01; cw10 = nw10; cw11 = nw11;
    }

    const f32x4 ow0 = *(const f32x4*)(cb + 448 + 8 * q);
    const f32x4 ow1 = *(const f32x4*)(cb + 448 + 8 * q + 4);
#pragma unroll
    for (int t = 0; t < 4; ++t) {
        float s = 0.f;
#pragma unroll
        for (int r = 0; r < 4; ++r)
            s += fmaxf(net[t][0][r], 0.f) * ow0[r] + fmaxf(net[t][1][r], 0.f) * ow1[r];
        s += __shfl_xor(s, 16, 64);
        s += __shfl_xor(s, 32, 64);
        if (q == 0)
            out[blockIdx.x * 256 + wave * 64 + t * 16 + m15] = s + cb[480];
    }
}

extern "C" void kernel_launch(void* const* d_in, const int* in_sizes, int n_in,
                              void* d_out, int out_size, void* d_ws, size_t ws_size,
                              hipStream_t stream) {
    const float* p        = (const float*)d_in[0];
    const float* c        = (const float*)d_in[2];
    const float* fc_p_w   = (const float*)d_in[4];
    const float* fc_p_b   = (const float*)d_in[5];
    const float* w0       = (const float*)d_in[6];
    const float* b0       = (const float*)d_in[7];
    const float* w1       = (const float*)d_in[8];
    const float* b1       = (const float*)d_in[9];
    const float* fc_out_w = (const float*)d_in[10];
    const float* fc_out_b = (const float*)d_in[11];
    float* out = (float*)d_out;

    unsigned short* wsf = (unsigned short*)d_ws;                  // 20480 B
    const size_t CF_OFF  = 32768;
    const size_t CF_SIZE = (size_t)16 * 65536 * 32 * 2;           // 64 MiB bf16 cf
    const dim3 grid(16 * 65536 / 256), block(256);

    hipLaunchKernelGGL(prep_weights, dim3(5), block, 0, stream, w0, w1, wsf);

    if (ws_size >= CF_OFF + CF_SIZE) {
        unsigned short* cfw = (unsigned short*)((char*)d_ws + CF_OFF);
        hipLaunchKernelGGL(interp_cf, grid, block, 0, stream, p, c, cfw);
        hipLaunchKernelGGL(decoder_split, grid, block, 0, stream,
                           p, fc_p_w, fc_p_b, b0, b1, fc_out_w, fc_out_b,
                           wsf, cfw, out);
    } else {
        hipLaunchKernelGGL(decoder_mfma, grid, block, 0, stream,
                           p, c, fc_p_w, fc_p_b, b0, b1,
                           fc_out_w, fc_out_b, wsf, out);
    }
}

// Round 12
// 146.344 us; speedup vs baseline: 1.7603x; 1.7603x over previous
//
#include <hip/hip_runtime.h>
#include <hip/hip_bf16.h>
#include <math.h>

// DecoderSphere B=16,T=65536,D=32. Round 12: COOPERATIVE GATHER.
// R11 split-ablation: interp gather alone = 139us == every fused variant
// (resnet rides free under it). interp is bound by per-instruction scatter
// degree: old gather = 32 instrs/wave x 64 DISTINCT 128B lines each (random
// grid rows per lane). New gather: lane l fetches chunk (l&7) of row
// pt=s*8+(l>>3) -> 8 contiguous lanes per 128B row -> 8 distinct lines per
// instruction (8x less scatter), same 32-instruction count. Row offsets +
// weights shared via per-wave LDS table (broadcast reads). 4-corner weighted
// sum accumulated in-lane in the same w11..w22 order => identical arithmetic
// to R8. Phase 2 (layer-outer ILPx4 resnet, cvt_pk pack, register-rotated
// weights) is verbatim R8.

typedef __attribute__((ext_vector_type(8))) short short8;
typedef __attribute__((ext_vector_type(4))) float f32x4;

#define CFW 36   // cf row stride in dwords (32 feats + 4 pad; pad holds p coords)

static __device__ __forceinline__ unsigned short f2bf(float x) {
    __hip_bfloat16 b = __float2bfloat16(x);
    unsigned short u;
    __builtin_memcpy(&u, &b, 2);
    return u;
}

// relu + pack two f32x4 accumulators into one bf16 x8 B-fragment (k=8q+j)
// via v_cvt_pk_bf16_f32 (lo = src0, hi = src1; HW RNE).
static __device__ __forceinline__ short8 pack2(f32x4 a, f32x4 b) {
    const float a0 = fmaxf(a[0], 0.f), a1 = fmaxf(a[1], 0.f);
    const float a2 = fmaxf(a[2], 0.f), a3 = fmaxf(a[3], 0.f);
    const float b0 = fmaxf(b[0], 0.f), b1 = fmaxf(b[1], 0.f);
    const float b2 = fmaxf(b[2], 0.f), b3 = fmaxf(b[3], 0.f);
    unsigned u0, u1, u2, u3;
    asm("v_cvt_pk_bf16_f32 %0, %1, %2" : "=v"(u0) : "v"(a0), "v"(a1));
    asm("v_cvt_pk_bf16_f32 %0, %1, %2" : "=v"(u1) : "v"(a2), "v"(a3));
    asm("v_cvt_pk_bf16_f32 %0, %1, %2" : "=v"(u2) : "v"(b0), "v"(b1));
    asm("v_cvt_pk_bf16_f32 %0, %1, %2" : "=v"(u3) : "v"(b2), "v"(b3));
    union { unsigned u[4]; short8 s; } cv;
    cv.u[0] = u0; cv.u[1] = u1; cv.u[2] = u2; cv.u[3] = u3;
    return cv.s;
}

// ---- prep: w0/w1 (f32, [5][32k][32f]) -> bf16 A-fragments in fragment order.
__global__ __launch_bounds__(256) void prep_weights(
    const float* __restrict__ w0g,
    const float* __restrict__ w1g,
    unsigned short* __restrict__ wsf)
{
    const int o = blockIdx.x * 256 + threadIdx.x;
    if (o >= 1280) return;
    const int lane = o & 63;
    const int h    = (o >> 6) & 1;
    const int mat  = (o >> 7) & 1;
    const int i    = o >> 8;
    const int q = lane >> 4, m15 = lane & 15;
    const int g0 = 8 * (m15 >> 2) + 4 * h + (m15 & 3);
    const float* src = (mat ? w1g : w0g) + i * 1024 + g0;
    union { unsigned short s[8]; short8 v; } r;
#pragma unroll
    for (int j = 0; j < 8; ++j)
        r.s[j] = f2bf(src[(8 * q + j) * 32]);
    *(short8*)(wsf + (size_t)o * 8) = r.v;
}

__global__ __launch_bounds__(256, 2) void decoder_mfma(
    const float* __restrict__ p,
    const float* __restrict__ c,
    const float* __restrict__ fc_p_w,
    const float* __restrict__ fc_p_b,
    const float* __restrict__ b0g,
    const float* __restrict__ b1g,
    const float* __restrict__ fc_out_w,
    const float* __restrict__ fc_out_b,
    const unsigned short* __restrict__ wsf,
    float* __restrict__ out)
{
    // layout (dwords): [0,9216) cfb 4x[64][36] | [9216,11264) tbl 4x256 uint2
    //                  [11264,11776) cb constants
    __shared__ float lds[11776];   // 47104 B
    const int tid  = threadIdx.x;
    const int wave = tid >> 6;
    const int lane = tid & 63;
    const int m15  = lane & 15;
    const int q    = lane >> 4;

    float* cfb = lds + wave * 2304;                      // [64 pts][36]
    uint2* tbl = (uint2*)(lds + 9216) + wave * 256;      // [4 corners][64 pts]
    float* cb  = lds + 11264;                            // constants [512]

    // ---- stage constants into LDS (once per block) ----
    for (int t = tid; t < 481; t += 256) {
        float v;
        if      (t < 96)  v = fc_p_w[t];
        else if (t < 128) v = fc_p_b[t - 96];
        else if (t < 288) v = b0g[t - 128];
        else if (t < 448) v = b1g[t - 288];
        else if (t < 480) v = fc_out_w[t - 448];
        else              v = fc_out_b[0];
        cb[t] = v;
    }

    __syncthreads();   // constants visible (only block barrier in the kernel)

    // ================= phase 1: cooperative interp (64 pts/wave) ==============
    const float PI_F = 3.1415927410125732f;
    const int g = blockIdx.x * 256 + tid;
    const int b = g >> 16;                      // T = 65536

    const float px = p[3 * g + 0];
    const float py = p[3 * g + 1];
    const float pz = p[3 * g + 2];

    const float lat = 90.0f - (atan2f(pz, sqrtf(px * px + py * py)) * 180.0f) / PI_F;
    const float mer = fmodf(360.0f + (atan2f(py, px) * 180.0f) / PI_F, 360.0f);

    const int xg = (int)floorf(mer / 5.625f);
    const int yg = (int)floorf(lat / 2.8125f);

    const int xl = (xg + 63) & 63;
    const int xr = (xg + 1) & 63;
    const int ylo = yg - 1 - ((yg - 1) >> 6);
    const int yhi = yg + 1 - ((yg + 1) >> 6);

    const float dx = (float)(xr - xg);
    const float dy = (float)(yhi - yg);

    const int yloi = ylo < 63 ? ylo : 63;
    const int yhii = yhi < 63 ? yhi : 63;

    const float w11 = dx * dy;
    const float w12 = (1.0f - dx) * dy;
    const float w21 = dx * (1.0f - dy);
    const float w22 = (1.0f - dx) * (1.0f - dy);

    // per-point row table: {dword offset within batch slice, weight}
    tbl[0 * 64 + lane] = make_uint2((unsigned)((xl * 64 + yloi) * 32), __float_as_uint(w11));
    tbl[1 * 64 + lane] = make_uint2((unsigned)((xr * 64 + yloi) * 32), __float_as_uint(w12));
    tbl[2 * 64 + lane] = make_uint2((unsigned)((xl * 64 + yhii) * 32), __float_as_uint(w21));
    tbl[3 * 64 + lane] = make_uint2((unsigned)((xr * 64 + yhii) * 32), __float_as_uint(w22));

    {   // p coords ride in the pad dwords [32..35] of this lane's cf row
        f32x4 pp = { px, py, pz, 0.f };
        *(f32x4*)(cfb + lane * CFW + 32) = pp;
    }

    __builtin_amdgcn_wave_barrier();   // table visible before cooperative reads

    // cooperative gather: lane fetches chunk (lane&7) of row pt = s*8+(lane>>3)
    // -> 8 contiguous lanes per 128B row, 8 distinct lines per instruction.
    {
        const float* cs = c + (size_t)b * (64 * 64 * 32);
        const int j     = lane >> 3;
        const int chunk = lane & 7;
#pragma unroll
        for (int s = 0; s < 8; ++s) {
            const int pt = s * 8 + j;
            f32x4 acc;
#pragma unroll
            for (int c4 = 0; c4 < 4; ++c4) {
                const uint2 e = tbl[c4 * 64 + pt];          // 8-lane broadcast
                const float w = __uint_as_float(e.y);
                const f32x4 d = *(const f32x4*)(cs + e.x + chunk * 4);
                if (c4 == 0) acc = w * d;
                else         acc = acc + w * d;             // same order as R8
            }
            *(f32x4*)(cfb + pt * CFW + chunk * 4) = acc;
        }
    }

    __builtin_amdgcn_wave_barrier();   // cf writes visible before phase-2 reads

    // ========== phase 2: layer-outer, 4 point-tiles in flight (verbatim R8) ====
    const short8* wsf8 = (const short8*)wsf;

    f32x4 net[4][2];
#pragma unroll
    for (int h = 0; h < 2; ++h) {
        const int fo = 8 * q + 4 * h;
        const f32x4 wx = *(const f32x4*)(cb + fo);
        const f32x4 wy = *(const f32x4*)(cb + 32 + fo);
        const f32x4 wz = *(const f32x4*)(cb + 64 + fo);
        const f32x4 bb = *(const f32x4*)(cb + 96 + fo);
#pragma unroll
        for (int t = 0; t < 4; ++t) {
            const f32x4 pp = *(const f32x4*)(cfb + (t * 16 + m15) * CFW + 32);
            net[t][h] = pp[0] * wx + pp[1] * wy + pp[2] * wz + bb;
        }
    }

    short8 cw00 = wsf8[lane];
    short8 cw01 = wsf8[64 + lane];
    short8 cw10 = wsf8[128 + lane];
    short8 cw11 = wsf8[192 + lane];

#pragma unroll 1
    for (int i = 0; i < 5; ++i) {
        const int ip = (i == 4) ? 0 : (i + 1);     // wrap: last prefetch unused
        const short8 nw00 = wsf8[ip * 256 + lane];
        const short8 nw01 = wsf8[ip * 256 + 64 + lane];
        const short8 nw10 = wsf8[ip * 256 + 128 + lane];
        const short8 nw11 = wsf8[ip * 256 + 192 + lane];

        const int b0o = 128 + i * 32 + 8 * q;
        const int b1o = 288 + i * 32 + 8 * q;
        const f32x4 bias00 = *(const f32x4*)(cb + b0o);
        const f32x4 bias01 = *(const f32x4*)(cb + b0o + 4);
        const f32x4 bias10 = *(const f32x4*)(cb + b1o);
        const f32x4 bias11 = *(const f32x4*)(cb + b1o + 4);

        short8 xf[4];
#pragma unroll
        for (int t = 0; t < 4; ++t) {
            const int co = (t * 16 + m15) * CFW + 8 * q;
            net[t][0] += *(const f32x4*)(cfb + co);
            net[t][1] += *(const f32x4*)(cfb + co + 4);
            xf[t] = pack2(net[t][0], net[t][1]);
        }

        f32x4 hh[4][2];
#pragma unroll
        for (int t = 0; t < 4; ++t) {
            hh[t][0] = __builtin_amdgcn_mfma_f32_16x16x32_bf16(cw00, xf[t], bias00, 0, 0, 0);
            hh[t][1] = __builtin_amdgcn_mfma_f32_16x16x32_bf16(cw01, xf[t], bias01, 0, 0, 0);
        }

#pragma unroll
        for (int t = 0; t < 4; ++t) {
            const short8 hf = pack2(hh[t][0], hh[t][1]);
            net[t][0] = __builtin_amdgcn_mfma_f32_16x16x32_bf16(cw10, hf, net[t][0], 0, 0, 0);
            net[t][1] = __builtin_amdgcn_mfma_f32_16x16x32_bf16(cw11, hf, net[t][1], 0, 0, 0);
        }

#pragma unroll
        for (int t = 0; t < 4; ++t) {
            net[t][0] += bias10;
            net[t][1] += bias11;
        }

        cw00 = nw00; cw01 = nw01; cw10 = nw10; cw11 = nw11;
    }

    // epilogue: out[pt] = sum_feat relu(net)*fc_out_w + fc_out_b
    const f32x4 ow0 = *(const f32x4*)(cb + 448 + 8 * q);
    const f32x4 ow1 = *(const f32x4*)(cb + 448 + 8 * q + 4);
#pragma unroll
    for (int t = 0; t < 4; ++t) {
        float s = 0.f;
#pragma unroll
        for (int r = 0; r < 4; ++r)
            s += fmaxf(net[t][0][r], 0.f) * ow0[r] + fmaxf(net[t][1][r], 0.f) * ow1[r];
        s += __shfl_xor(s, 16, 64);
        s += __shfl_xor(s, 32, 64);
        if (q == 0)
            out[blockIdx.x * 256 + wave * 64 + t * 16 + m15] = s + cb[480];
    }
}

extern "C" void kernel_launch(void* const* d_in, const int* in_sizes, int n_in,
                              void* d_out, int out_size, void* d_ws, size_t ws_size,
                              hipStream_t stream) {
    const float* p        = (const float*)d_in[0];
    const float* c        = (const float*)d_in[2];
    const float* fc_p_w   = (const float*)d_in[4];
    const float* fc_p_b   = (const float*)d_in[5];
    const float* w0       = (const float*)d_in[6];
    const float* b0       = (const float*)d_in[7];
    const float* w1       = (const float*)d_in[8];
    const float* b1       = (const float*)d_in[9];
    const float* fc_out_w = (const float*)d_in[10];
    const float* fc_out_b = (const float*)d_in[11];
    float* out = (float*)d_out;
    unsigned short* wsf = (unsigned short*)d_ws;   // 20480 B of bf16 fragments

    hipLaunchKernelGGL(prep_weights, dim3(5), dim3(256), 0, stream, w0, w1, wsf);
    hipLaunchKernelGGL(decoder_mfma, dim3((16 * 65536) / 256), dim3(256), 0, stream,
                       p, c, fc_p_w, fc_p_b, b0, b1,
                       fc_out_w, fc_out_b, wsf, out);
}